// Round 22
// baseline (725.219 us; speedup 1.0000x reference)
//
#include <hip/hip_runtime.h>
#include <stdint.h>

// ---------------------------------------------------------------------------
// LatticeCNN on MI355X — round 30 (= round 26 held stable for measurement).
//
// Math (validated rounds 2-7):
//   out(x,y) = leaky( X[x,y]·W1[clsx][clsy] + P2 + P3 + P4 + bias )
//   P3 = sum_{a'<px} X[24+a',y]·AS[a'][py]      (px = max(x-24,0))
//   P2 = sum_{b'<py} X[x,24+b']·SB[px][b']      (py = max(y-24,0))
//   P4 = sum_{a'<px,b'<py} X[24+a',24+b']·M[a'][b']
//   Wall[slot][gf] = sum_k L[slot][k]·PBg[gf][k], K=128=[mw;jw], L closed-form.
//
// Measurements: R16 255.2 (final 2x42.3 @ Occ15%/Mfma1.7% latency-bound),
// R20 244.8 (occ/vec4 fixes), R25 252.8 (max-TLP splits NEUTRAL; per-
// dispatch tuning exhausted; plateau ~250 with ~83 µs harness fills).
// R26 (carried, unmeasured — structural): corr_gemm DELETED; corrections
// MFMA-recomputed inside final_gemm into the same fp32 acc (C-in
// additive; MFMA pipes ~2% busy = recompute is free; equivalence
// audited 4x, incl. bf16-precision and A1-dependency checks). Removes
// 2 dispatches + 2 gaps + V/U/T HBM round-trip. 5 dispatches.
// R30: held stable — R26 must be measured alone.
//
// Workspace (~75MB of 256MB):
//   Xt0@0 (8.4) | A1@9 (16.8) | Wall0@26 (7.4) | Wall1@34 (14.7)
//   Out2@49 (16.8) | PBg0@66 (2.1) | PBg1@69 (4.2) | L@74 | bias/flag@75
// ---------------------------------------------------------------------------

typedef __attribute__((ext_vector_type(8))) short short8;
typedef __attribute__((ext_vector_type(4))) float floatx4;
typedef __attribute__((ext_vector_type(4))) unsigned short ushort4v;

__device__ __forceinline__ float bf2f(unsigned short u) {
  union { uint32_t u; float f; } c; c.u = ((uint32_t)u) << 16; return c.f;
}
__device__ __forceinline__ unsigned short f2bf(float f) {
  union { float f; uint32_t u; } c; c.f = f;
  uint32_t u = c.u;
  uint32_t r = (u + 0x7FFFu + ((u >> 16) & 1u)) >> 16;
  return (unsigned short)r;
}

// Weight slot bases inside Wall [slot][G][F]
#define SLOT_W1 0    // 225 combined pointwise slots (clsx*15+clsy)
#define SLOT_SB 225  // 64 slots (px*8+b)
#define SLOT_AS 289  // 64 slots (a*8+py)
#define SLOT_M  353  // 64 slots (a*8+b)
#define N_SLOTS 417
#define N_SLOTS_PAD 448

// Fused front-end: one dispatch, three independent jobs selected by bid.
//   [0, 225)        setup: block 0 = dtype detect + bias + flag store;
//                   blocks 1..224 = closed-form L[448][128] bf16.
//   [225, 1249)     pack mw||jw -> PBg[g*F+f][k=128] bf16 (LDS f<->g swap).
//   [1249, 5345)    transpose x [4096][1024] -> Xt0 [pos][m][f] bf16 (vec4).
// pack/transpose blocks recompute the dtype flag locally.
#define NB_SETUP 225
#define NB_PACK 1024
#define NB_TIN 4096
__global__ __launch_bounds__(256) void fused_prep(
    const unsigned short* __restrict__ xa,  // x viewed as bf16 words
    const float* __restrict__ x32,          // x viewed as fp32
    const void* __restrict__ mw0, const void* __restrict__ jw0,
    const void* __restrict__ mw1, const void* __restrict__ jw1,
    const void* __restrict__ mb0, const void* __restrict__ jb0,
    const void* __restrict__ mb1, const void* __restrict__ jb1,
    float* __restrict__ bias0, float* __restrict__ bias1,
    int* __restrict__ flag, unsigned short* __restrict__ L,
    unsigned short* __restrict__ PBg0, unsigned short* __restrict__ PBg1,
    unsigned short* __restrict__ Xt0) {
  __shared__ int s_cnt;
  __shared__ unsigned short sh_pack[128][33];  // pack branch
  __shared__ unsigned short sh_tile[32][33];   // transpose branch
  int tx = threadIdx.x, ty = threadIdx.y;
  int tid = ty * 32 + tx;
  int bid = blockIdx.x;

  if (bid < NB_SETUP) {
    if (bid == 0) {
      if (tid == 0) s_cnt = 0;
      __syncthreads();
      unsigned short v = xa[tid];
      int e = (v >> 7) & 0xFF;
      int ok = (v == 0) || (e >= 110 && e <= 140);
      atomicAdd(&s_cnt, ok);
      __syncthreads();
      int fp32 = (s_cnt >= 240) ? 0 : 1;
      if (tid == 0) *flag = fp32;
      int g = tid & 127;
      const void* mb = (tid < 128) ? mb0 : mb1;
      const void* jb = (tid < 128) ? jb0 : jb1;
      float* bo = (tid < 128) ? bias0 : bias1;
      float m = fp32 ? ((const float*)mb)[g] : bf2f(((const unsigned short*)mb)[g]);
      float j = fp32 ? ((const float*)jb)[g] : bf2f(((const unsigned short*)jb)[g]);
      bo[g] = 0.5f * (m + j);
      return;
    }
    int t = (bid - 1) * 256 + tid;  // 224*256 = 448*128
    int slot = t >> 7, k = t & 127;
    int isj = k >= 64, ab = k & 63, a = ab >> 3, b = ab & 7;
    float v = 0.f;
    if (slot < 225) {
      int cx = slot / 15, cy = slot % 15;
      int pmx = cx < 7 ? cx : 7, pxx = cx > 7 ? cx - 7 : 0;
      int pmy = cy < 7 ? cy : 7, pyy = cy > 7 ? cy - 7 : 0;
      if (!isj) v = (a >= pxx && b >= pyy) ? 0.5f : 0.f;
      else      v = (a <= pmx && b <= pmy) ? 0.5f : 0.f;
    } else if (slot < 289) {
      int s = slot - SLOT_SB, px = s >> 3, b0 = s & 7;
      if (!isj) v = (a >= px && b == b0) ? 0.5f : 0.f;
    } else if (slot < 353) {
      int s = slot - SLOT_AS, a0 = s >> 3, py = s & 7;
      if (!isj) v = (a == a0 && b >= py) ? 0.5f : 0.f;
    } else if (slot < 417) {
      int s = slot - SLOT_M, a0 = s >> 3, b0 = s & 7;
      if (!isj) v = (a == a0 && b == b0) ? 0.5f : 0.f;
    }
    L[t] = f2bf(v);
    return;
  }

  // ---- local dtype detect (pack & transpose branches) ----
  if (tid == 0) s_cnt = 0;
  __syncthreads();
  {
    unsigned short v = xa[tid];
    int e = (v >> 7) & 0xFF;
    int ok = (v == 0) || (e >= 110 && e <= 140);
    atomicAdd(&s_cnt, ok);
  }
  __syncthreads();
  int fp32 = (s_cnt >= 240) ? 0 : 1;

  if (bid < NB_SETUP + NB_PACK) {
    // pack_weights: grid (4 g-tiles, 128 f, 2 layers), layer0 f>=64 exit.
    int pb = bid - NB_SETUP;
    int gx = pb & 3, gy = (pb >> 2) & 127, layer = pb >> 9;
    int F = layer ? 128 : 64;
    int f = gy;
    if (f >= F) return;
    int g0 = gx * 32;
    const int G = 128, FG = F * G;
    const void* mw = layer ? mw1 : mw0;
    const void* jw = layer ? jw1 : jw0;
    unsigned short* PB = layer ? PBg1 : PBg0;
    for (int k = ty; k < 128; k += 8) {
      const void* src = (k < 64) ? mw : jw;
      int ab = k & 63;
      size_t idx = (size_t)ab * FG + (size_t)f * G + g0 + tx;
      sh_pack[k][tx] = fp32 ? f2bf(((const float*)src)[idx])
                            : ((const unsigned short*)src)[idx];
    }
    __syncthreads();
    int kk = tid & 127, gs = tid >> 7;  // gs in {0,1}
    for (int gg = gs; gg < 32; gg += 2)
      PB[((size_t)(g0 + gg) * F + f) * 128 + kk] = sh_pack[kk][gg];
    return;
  }

  // transpose_in: x [R=4096][C=1024] -> Xt0 [C][R] bf16, vec4 both sides.
  {
    int tbi = bid - (NB_SETUP + NB_PACK);
    const int R = 4096, C = 1024;
    int c0 = (tbi & 31) * 32, r0 = (tbi >> 5) * 32;
    int row = tid >> 3, vc = tid & 7;
    if (fp32) {
      floatx4 lv = *(const floatx4*)&x32[(size_t)(r0 + row) * C + c0 + vc * 4];
#pragma unroll
      for (int j = 0; j < 4; ++j) sh_tile[row][vc * 4 + j] = f2bf(lv[j]);
    } else {
      ushort4v lv = *(const ushort4v*)&xa[(size_t)(r0 + row) * C + c0 + vc * 4];
#pragma unroll
      for (int j = 0; j < 4; ++j) sh_tile[row][vc * 4 + j] = lv[j];
    }
    __syncthreads();
    ushort4v w;
#pragma unroll
    for (int j = 0; j < 4; ++j) w[j] = sh_tile[vc * 4 + j][row];
    *(ushort4v*)&Xt0[(size_t)(c0 + row) * R + r0 + vc * 4] = w;
  }
}

// Transpose src[R][C] (bf16) -> dst[C][R]; dst fp32 or bf16 per flag.
// Vectorized: block (8,32); lane loads ushort4, stores ushort4/float4.
__global__ __launch_bounds__(256) void transpose_out(
    const unsigned short* __restrict__ src, unsigned short* __restrict__ d16,
    float* __restrict__ d32, int R, int C, const int* __restrict__ flag) {
  __shared__ unsigned short tile[32][33];
  int fp32 = *flag;
  int tx = threadIdx.x, ty = threadIdx.y;  // tx in [0,8), ty in [0,32)
  int c0 = blockIdx.x * 32, r0 = blockIdx.y * 32;
  ushort4v v = *(const ushort4v*)&src[(size_t)(r0 + ty) * C + c0 + tx * 4];
#pragma unroll
  for (int j = 0; j < 4; ++j) tile[ty][tx * 4 + j] = v[j];
  __syncthreads();
  if (fp32) {
    floatx4 w;
#pragma unroll
    for (int j = 0; j < 4; ++j) w[j] = bf2f(tile[tx * 4 + j][ty]);
    *(floatx4*)&d32[(size_t)(c0 + ty) * R + r0 + tx * 4] = w;
  } else {
    ushort4v w;
#pragma unroll
    for (int j = 0; j < 4; ++j) w[j] = tile[tx * 4 + j][ty];
    *(ushort4v*)&d16[(size_t)(c0 + ty) * R + r0 + tx * 4] = w;
  }
}

// MFMA core: acc[64m x (16*NT)g] += A[64m x K] * Wt[g x K]^T (W pre-offset).
// A fragment: lane holds A[m=lane&15][k=(lane>>4)*8+j]   (16B load)
// B fragment: lane holds Wt[n=lane&15][k=(lane>>4)*8+j]  (16B load)
template <int F, int NT>
__device__ __forceinline__ void mfma_tile(
    const unsigned short* __restrict__ A, const unsigned short* __restrict__ W,
    floatx4 acc[NT], int wave, int n, int q) {
  const unsigned short* a_ptr = A + ((size_t)(wave * 16 + n)) * F + q * 8;
  const unsigned short* w_ptr = W + (size_t)n * F + q * 8;
#pragma unroll
  for (int kk = 0; kk < F; kk += 32) {
    short8 av = *(const short8*)(a_ptr + kk);
#pragma unroll
    for (int t = 0; t < NT; ++t) {
      short8 bv = *(const short8*)(w_ptr + (size_t)t * 16 * F + kk);
      acc[t] = __builtin_amdgcn_mfma_f32_16x16x32_bf16(av, bv, acc[t], 0, 0, 0);
    }
  }
}

// Prep GEMM: Wall[slot][gf] = sum_k L[slot][k]*PBg[gf][k]. Direct store.
// grid (512 n-tiles of 32 gf, 7 m-tiles, 2 layers), NT=2,
// launch_bounds(256,8). Layer0 (GF=8192) blocks with n0>=GF exit.
__global__ __launch_bounds__(256, 8) void prep_gemm2(
    const unsigned short* __restrict__ L,
    const unsigned short* __restrict__ PBg0,
    const unsigned short* __restrict__ PBg1,
    unsigned short* __restrict__ Wall0, unsigned short* __restrict__ Wall1) {
  int layer = blockIdx.z;
  int GF = layer ? 16384 : 8192;
  int n0 = blockIdx.x * 32;
  if (n0 >= GF) return;
  int m0 = blockIdx.y * 64;
  const unsigned short* PB = layer ? PBg1 : PBg0;
  unsigned short* Wall = layer ? Wall1 : Wall0;
  int wave = threadIdx.x >> 6, lane = threadIdx.x & 63;
  int n = lane & 15, q = lane >> 4;
  floatx4 acc[2];
#pragma unroll
  for (int t = 0; t < 2; ++t) acc[t] = (floatx4){0.f, 0.f, 0.f, 0.f};
  mfma_tile<128, 2>(L + (size_t)m0 * 128, PB + (size_t)n0 * 128, acc, wave, n, q);
#pragma unroll
  for (int t = 0; t < 2; ++t) {
    int gcol = n0 + t * 16 + n;
#pragma unroll
    for (int r = 0; r < 4; ++r) {
      int m = m0 + wave * 16 + q * 4 + r;  // C/D: row=(lane>>4)*4+reg
      Wall[(size_t)m * GF + gcol] = f2bf(acc[t][r]);
    }
  }
}

// Accumulate one (ipos, slot) MFMA tile into acc[2] (32 g-cols at gsoff).
template <int F>
__device__ __forceinline__ void acc_slot(
    const unsigned short* __restrict__ Xt, const unsigned short* __restrict__ Wall,
    int ipos, int slot, int gsoff, floatx4 acc[2], int wave, int n, int q) {
  mfma_tile<F, 2>(Xt + (size_t)ipos * 64 * F,
                  Wall + ((size_t)slot * 128 + gsoff) * F, acc, wave, n, q);
}

// term1 + RECOMPUTED corrections + bias + leaky-relu, one kernel.
// grid (1024, 4): gs = 32-g-col quarter; launch_bounds(256,8).
// All correction terms are extra MFMA tiles into the same fp32 acc
// (C-in additive; MFMA pipes ~2% busy so recompute is free). Slot/ipos
// algebra identical to the retired corr_gemm path (audited 4x):
//   P3: a'=0..px-1: A=Xt[(24+a')*32+y],    slot=SLOT_AS+a'*8+py
//   P2: b'=0..py-1: A=Xt[x*32+24+b'],      slot=SLOT_SB+px*8+b'
//   P4: (a',b')<(px,py): A=Xt[(24+a')*32+24+b'], slot=SLOT_M+a'*8+b'
// Loop bounds wave-uniform (same pos per block) — no divergence.
template <int F>
__global__ __launch_bounds__(256, 8) void final_gemm(
    const unsigned short* __restrict__ Xt, const unsigned short* __restrict__ Wall,
    const float* __restrict__ bias, unsigned short* __restrict__ Out) {
  int pos = blockIdx.x, gs = blockIdx.y;  // gs in [0,4)
  int x = pos >> 5, y = pos & 31;
  int wave = threadIdx.x >> 6, lane = threadIdx.x & 63;
  int n = lane & 15, q = lane >> 4;
  int m0 = wave * 16 + q * 4;
  int clsx = x < 7 ? x : (x <= 24 ? 7 : x - 17);
  int clsy = y < 7 ? y : (y <= 24 ? 7 : y - 17);
  int px = x > 24 ? x - 24 : 0;
  int py = y > 24 ? y - 24 : 0;
  int gsoff = gs * 32;

  floatx4 acc[2];
#pragma unroll
  for (int t = 0; t < 2; ++t) {
    float bv = bias[gsoff + t * 16 + n];
#pragma unroll
    for (int r = 0; r < 4; ++r) acc[t][r] = bv;
  }

  // Main pointwise term.
  acc_slot<F>(Xt, Wall, pos, SLOT_W1 + clsx * 15 + clsy, gsoff, acc, wave, n, q);
  // P3 (column correction).
  for (int a2 = 0; a2 < px; ++a2)
    acc_slot<F>(Xt, Wall, (24 + a2) * 32 + y, SLOT_AS + a2 * 8 + py, gsoff,
                acc, wave, n, q);
  // P2 (row correction).
  for (int b2 = 0; b2 < py; ++b2)
    acc_slot<F>(Xt, Wall, x * 32 + 24 + b2, SLOT_SB + px * 8 + b2, gsoff,
                acc, wave, n, q);
  // P4 (corner correction).
  for (int a2 = 0; a2 < px; ++a2)
    for (int b2 = 0; b2 < py; ++b2)
      acc_slot<F>(Xt, Wall, (24 + a2) * 32 + 24 + b2, SLOT_M + a2 * 8 + b2,
                  gsoff, acc, wave, n, q);

  unsigned short* o = Out + (size_t)pos * 64 * 128;
#pragma unroll
  for (int t = 0; t < 2; ++t) {
    int gcol = gsoff + t * 16 + n;
#pragma unroll
    for (int r = 0; r < 4; ++r) {
      int m = m0 + r;  // C/D layout: row=(lane>>4)*4+reg
      float v = acc[t][r];
      v = v > 0.f ? v : 0.01f * v;
      o[(size_t)m * 128 + gcol] = f2bf(v);
    }
  }
}

extern "C" void kernel_launch(void* const* d_in, const int* in_sizes, int n_in,
                              void* d_out, int out_size, void* d_ws,
                              size_t ws_size, hipStream_t stream) {
  const void* x   = d_in[0];
  const void* mw0 = d_in[5];
  const void* mb0 = d_in[6];
  const void* jw0 = d_in[7];
  const void* jb0 = d_in[8];
  const void* mw1 = d_in[9];
  const void* mb1 = d_in[10];
  const void* jw1 = d_in[11];
  const void* jb1 = d_in[12];

  char* ws = (char*)d_ws;
  const size_t MB = 1u << 20;
  unsigned short* Xt0   = (unsigned short*)(ws + 0);        // 8.4 MB
  unsigned short* A1    = (unsigned short*)(ws + 9 * MB);   // 16.8 MB
  unsigned short* Wall0 = (unsigned short*)(ws + 26 * MB);  // 7.4 MB (448)
  unsigned short* Wall1 = (unsigned short*)(ws + 34 * MB);  // 14.7 MB (448)
  unsigned short* Out2  = (unsigned short*)(ws + 49 * MB);  // 16.8 MB
  unsigned short* PBg0  = (unsigned short*)(ws + 66 * MB);  // 2.1 MB
  unsigned short* PBg1  = (unsigned short*)(ws + 69 * MB);  // 4.2 MB
  unsigned short* L     = (unsigned short*)(ws + 74 * MB);  // 114 KB
  float* bias0 = (float*)(ws + 75 * MB);
  float* bias1 = bias0 + 128;
  int*   flag  = (int*)(bias1 + 128);

  dim3 tb(32, 8);
  // Fused setup + weight-pack + input-transpose (independent jobs).
  fused_prep<<<NB_SETUP + NB_PACK + NB_TIN, tb, 0, stream>>>(
      (const unsigned short*)x, (const float*)x, mw0, jw0, mw1, jw1,
      mb0, jb0, mb1, jb1, bias0, bias1, flag, L, PBg0, PBg1, Xt0);
  prep_gemm2<<<dim3(512, 7, 2), 256, 0, stream>>>(L, PBg0, PBg1, Wall0, Wall1);

  // ---- Layer 1 (F=64) ----
  final_gemm<64><<<dim3(1024, 4), 256, 0, stream>>>(Xt0, Wall0, bias0, A1);
  // ---- Layer 2 (F=128) ----
  final_gemm<128><<<dim3(1024, 4), 256, 0, stream>>>(A1, Wall1, bias1, Out2);

  // Out2 [pos=1024][m*128+g=8192] -> d_out [m][g][pos]; vec4 block (8,32).
  transpose_out<<<dim3(256, 32), dim3(8, 32), 0, stream>>>(
      Out2, (unsigned short*)d_out, (float*)d_out, 1024, 8192, flag);
}

// Round 24
// 244.671 us; speedup vs baseline: 2.9641x; 2.9641x over previous
//
#include <hip/hip_runtime.h>
#include <stdint.h>

// ---------------------------------------------------------------------------
// LatticeCNN on MI355X — round 32 (= R20/R31 measured-best, held for confirm).
//
// R26/R30 measured 725.2 µs — 3x REGRESSION (inline correction recompute:
// serial dependent chains + 1..64-tile imbalance + 3.5x duplicated work).
// Reverted in R31 to the exact R20 stack (measured 244.8 µs, Round 12):
// final_gemm grid (1024,2)/NT=4 with A-preload; corr_gemm grid (72,4)/
// NT=2; V/U/T in [gcol][64m] vec4 layout; prep_gemm2 NT=8; scan-free
// (T row-prefixed, a-prefix at read). 7 dispatches.
// R32: held stable awaiting confirmation bench. Lesson ledger: R17-R19
// validated wins; R21/R22/R24 neutral; R26 falsified (inline recompute
// is latency-catastrophic despite idle MFMA pipes — the dependent-acc
// chain serializes, and corner blocks form a 64-tile tail).
//
// Math (validated):
//   out(x,y) = leaky( X[x,y]·W1[clsx][clsy] + P2 + P3 + P4 + bias )
//   P3 = prefix_a of V[a][y] = X[24+a,y]·AS[a][py]
//   P2 = prefix_b of U[b][x] = X[x,24+b]·SB[px][b]
//   P4 = 2D prefix of T[a][b] = X[24+a,24+b]·mw[a][b]
//   Wall[slot][gf] = sum_k L[slot][k]·PBg[gf][k], K=128=[mw;jw].
//
// Workspace (~88MB of 256MB):
//   Xt0@0 (8.4) | A1@9 (16.8) | Wall0@26 (7.4) | Wall1@34 (14.7)
//   Out2@49 (16.8) | PBg0@66 (2.1) | PBg1@69 (4.2) | L@74 | bias/flag@75
//   V@76 (4.2) | U@81 (4.2) | T@86 (1.05)   (bf16 corrections, [gcol][64m])
// ---------------------------------------------------------------------------

typedef __attribute__((ext_vector_type(8))) short short8;
typedef __attribute__((ext_vector_type(4))) float floatx4;
typedef __attribute__((ext_vector_type(4))) unsigned short ushort4v;

__device__ __forceinline__ float bf2f(unsigned short u) {
  union { uint32_t u; float f; } c; c.u = ((uint32_t)u) << 16; return c.f;
}
__device__ __forceinline__ unsigned short f2bf(float f) {
  union { float f; uint32_t u; } c; c.f = f;
  uint32_t u = c.u;
  uint32_t r = (u + 0x7FFFu + ((u >> 16) & 1u)) >> 16;
  return (unsigned short)r;
}

// Weight slot bases inside Wall [slot][G][F]
#define SLOT_W1 0    // 225 combined pointwise slots (clsx*15+clsy)
#define SLOT_SB 225  // 64 slots (px*8+b)
#define SLOT_AS 289  // 64 slots (a*8+py)
#define SLOT_M  353  // 64 slots (a*8+b)
#define N_SLOTS 417
#define N_SLOTS_PAD 448

// Fused front-end: one dispatch, three independent jobs selected by bid.
#define NB_SETUP 225
#define NB_PACK 1024
#define NB_TIN 4096
__global__ __launch_bounds__(256) void fused_prep(
    const unsigned short* __restrict__ xa,  // x viewed as bf16 words
    const float* __restrict__ x32,          // x viewed as fp32
    const void* __restrict__ mw0, const void* __restrict__ jw0,
    const void* __restrict__ mw1, const void* __restrict__ jw1,
    const void* __restrict__ mb0, const void* __restrict__ jb0,
    const void* __restrict__ mb1, const void* __restrict__ jb1,
    float* __restrict__ bias0, float* __restrict__ bias1,
    int* __restrict__ flag, unsigned short* __restrict__ L,
    unsigned short* __restrict__ PBg0, unsigned short* __restrict__ PBg1,
    unsigned short* __restrict__ Xt0) {
  __shared__ int s_cnt;
  __shared__ unsigned short sh_pack[128][33];  // pack branch
  __shared__ unsigned short sh_tile[32][33];   // transpose branch
  int tx = threadIdx.x, ty = threadIdx.y;
  int tid = ty * 32 + tx;
  int bid = blockIdx.x;

  if (bid < NB_SETUP) {
    if (bid == 0) {
      if (tid == 0) s_cnt = 0;
      __syncthreads();
      unsigned short v = xa[tid];
      int e = (v >> 7) & 0xFF;
      int ok = (v == 0) || (e >= 110 && e <= 140);
      atomicAdd(&s_cnt, ok);
      __syncthreads();
      int fp32 = (s_cnt >= 240) ? 0 : 1;
      if (tid == 0) *flag = fp32;
      int g = tid & 127;
      const void* mb = (tid < 128) ? mb0 : mb1;
      const void* jb = (tid < 128) ? jb0 : jb1;
      float* bo = (tid < 128) ? bias0 : bias1;
      float m = fp32 ? ((const float*)mb)[g] : bf2f(((const unsigned short*)mb)[g]);
      float j = fp32 ? ((const float*)jb)[g] : bf2f(((const unsigned short*)jb)[g]);
      bo[g] = 0.5f * (m + j);
      return;
    }
    int t = (bid - 1) * 256 + tid;  // 224*256 = 448*128
    int slot = t >> 7, k = t & 127;
    int isj = k >= 64, ab = k & 63, a = ab >> 3, b = ab & 7;
    float v = 0.f;
    if (slot < 225) {
      int cx = slot / 15, cy = slot % 15;
      int pmx = cx < 7 ? cx : 7, pxx = cx > 7 ? cx - 7 : 0;
      int pmy = cy < 7 ? cy : 7, pyy = cy > 7 ? cy - 7 : 0;
      if (!isj) v = (a >= pxx && b >= pyy) ? 0.5f : 0.f;
      else      v = (a <= pmx && b <= pmy) ? 0.5f : 0.f;
    } else if (slot < 289) {
      int s = slot - SLOT_SB, px = s >> 3, b0 = s & 7;
      if (!isj) v = (a >= px && b == b0) ? 0.5f : 0.f;
    } else if (slot < 353) {
      int s = slot - SLOT_AS, a0 = s >> 3, py = s & 7;
      if (!isj) v = (a == a0 && b >= py) ? 0.5f : 0.f;
    } else if (slot < 417) {
      int s = slot - SLOT_M, a0 = s >> 3, b0 = s & 7;
      if (!isj) v = (a == a0 && b == b0) ? 0.5f : 0.f;
    }
    L[t] = f2bf(v);
    return;
  }

  // ---- local dtype detect (pack & transpose branches) ----
  if (tid == 0) s_cnt = 0;
  __syncthreads();
  {
    unsigned short v = xa[tid];
    int e = (v >> 7) & 0xFF;
    int ok = (v == 0) || (e >= 110 && e <= 140);
    atomicAdd(&s_cnt, ok);
  }
  __syncthreads();
  int fp32 = (s_cnt >= 240) ? 0 : 1;

  if (bid < NB_SETUP + NB_PACK) {
    // pack_weights: grid (4 g-tiles, 128 f, 2 layers), layer0 f>=64 exit.
    int pb = bid - NB_SETUP;
    int gx = pb & 3, gy = (pb >> 2) & 127, layer = pb >> 9;
    int F = layer ? 128 : 64;
    int f = gy;
    if (f >= F) return;
    int g0 = gx * 32;
    const int G = 128, FG = F * G;
    const void* mw = layer ? mw1 : mw0;
    const void* jw = layer ? jw1 : jw0;
    unsigned short* PB = layer ? PBg1 : PBg0;
    for (int k = ty; k < 128; k += 8) {
      const void* src = (k < 64) ? mw : jw;
      int ab = k & 63;
      size_t idx = (size_t)ab * FG + (size_t)f * G + g0 + tx;
      sh_pack[k][tx] = fp32 ? f2bf(((const float*)src)[idx])
                            : ((const unsigned short*)src)[idx];
    }
    __syncthreads();
    int kk = tid & 127, gs = tid >> 7;  // gs in {0,1}
    for (int gg = gs; gg < 32; gg += 2)
      PB[((size_t)(g0 + gg) * F + f) * 128 + kk] = sh_pack[kk][gg];
    return;
  }

  // transpose_in: x [R=4096][C=1024] -> Xt0 [C][R] bf16, vec4 both sides.
  {
    int tbi = bid - (NB_SETUP + NB_PACK);
    const int R = 4096, C = 1024;
    int c0 = (tbi & 31) * 32, r0 = (tbi >> 5) * 32;
    int row = tid >> 3, vc = tid & 7;
    if (fp32) {
      floatx4 lv = *(const floatx4*)&x32[(size_t)(r0 + row) * C + c0 + vc * 4];
#pragma unroll
      for (int j = 0; j < 4; ++j) sh_tile[row][vc * 4 + j] = f2bf(lv[j]);
    } else {
      ushort4v lv = *(const ushort4v*)&xa[(size_t)(r0 + row) * C + c0 + vc * 4];
#pragma unroll
      for (int j = 0; j < 4; ++j) sh_tile[row][vc * 4 + j] = lv[j];
    }
    __syncthreads();
    ushort4v w;
#pragma unroll
    for (int j = 0; j < 4; ++j) w[j] = sh_tile[vc * 4 + j][row];
    *(ushort4v*)&Xt0[(size_t)(c0 + row) * R + r0 + vc * 4] = w;
  }
}

// Transpose src[R][C] (bf16) -> dst[C][R]; dst fp32 or bf16 per flag.
__global__ __launch_bounds__(256) void transpose_out(
    const unsigned short* __restrict__ src, unsigned short* __restrict__ d16,
    float* __restrict__ d32, int R, int C, const int* __restrict__ flag) {
  __shared__ unsigned short tile[32][33];
  int fp32 = *flag;
  int tx = threadIdx.x, ty = threadIdx.y;  // tx in [0,8), ty in [0,32)
  int c0 = blockIdx.x * 32, r0 = blockIdx.y * 32;
  ushort4v v = *(const ushort4v*)&src[(size_t)(r0 + ty) * C + c0 + tx * 4];
#pragma unroll
  for (int j = 0; j < 4; ++j) tile[ty][tx * 4 + j] = v[j];
  __syncthreads();
  if (fp32) {
    floatx4 w;
#pragma unroll
    for (int j = 0; j < 4; ++j) w[j] = bf2f(tile[tx * 4 + j][ty]);
    *(floatx4*)&d32[(size_t)(c0 + ty) * R + r0 + tx * 4] = w;
  } else {
    ushort4v w;
#pragma unroll
    for (int j = 0; j < 4; ++j) w[j] = tile[tx * 4 + j][ty];
    *(ushort4v*)&d16[(size_t)(c0 + ty) * R + r0 + tx * 4] = w;
  }
}

// MFMA core: acc[64m x (16*NT)g] += A[64m x K] * Wt[g x K]^T (W pre-offset).
template <int F, int NT>
__device__ __forceinline__ void mfma_tile(
    const unsigned short* __restrict__ A, const unsigned short* __restrict__ W,
    floatx4 acc[NT], int wave, int n, int q) {
  const unsigned short* a_ptr = A + ((size_t)(wave * 16 + n)) * F + q * 8;
  const unsigned short* w_ptr = W + (size_t)n * F + q * 8;
#pragma unroll
  for (int kk = 0; kk < F; kk += 32) {
    short8 av = *(const short8*)(a_ptr + kk);
#pragma unroll
    for (int t = 0; t < NT; ++t) {
      short8 bv = *(const short8*)(w_ptr + (size_t)t * 16 * F + kk);
      acc[t] = __builtin_amdgcn_mfma_f32_16x16x32_bf16(av, bv, acc[t], 0, 0, 0);
    }
  }
}

// Prep GEMM: Wall[slot][gf] = sum_k L[slot][k]*PBg[gf][k]. Direct store.
// grid (n-tiles of 128 gf, 7 m-tiles of 64 slots, 2 layers).
__global__ __launch_bounds__(256) void prep_gemm2(
    const unsigned short* __restrict__ L,
    const unsigned short* __restrict__ PBg0,
    const unsigned short* __restrict__ PBg1,
    unsigned short* __restrict__ Wall0, unsigned short* __restrict__ Wall1) {
  int layer = blockIdx.z;
  int GF = layer ? 16384 : 8192;
  int n0 = blockIdx.x * 128;
  if (n0 >= GF) return;
  int m0 = blockIdx.y * 64;
  const unsigned short* PB = layer ? PBg1 : PBg0;
  unsigned short* Wall = layer ? Wall1 : Wall0;
  int wave = threadIdx.x >> 6, lane = threadIdx.x & 63;
  int n = lane & 15, q = lane >> 4;
  floatx4 acc[8];
#pragma unroll
  for (int t = 0; t < 8; ++t) acc[t] = (floatx4){0.f, 0.f, 0.f, 0.f};
  mfma_tile<128, 8>(L + (size_t)m0 * 128, PB + (size_t)n0 * 128, acc, wave, n, q);
#pragma unroll
  for (int t = 0; t < 8; ++t) {
    int gcol = n0 + t * 16 + n;
#pragma unroll
    for (int r = 0; r < 4; ++r) {
      int m = m0 + wave * 16 + q * 4 + r;  // C/D: row=(lane>>4)*4+reg
      Wall[(size_t)m * GF + gcol] = f2bf(acc[t][r]);
    }
  }
}

// Correction matmuls WITH fused prefix (accumulator-carry): grid (72, 4).
// gsh = blockIdx.y selects a 32-wide g-quarter (prefix per-column
// independent; 288 blocks). OUTPUT LAYOUT: slice[gcol*64 + m] (vec4
// stores here, vec4 loads in final_gemm; m0 = wave*16+q*4 is 4-aligned).
//   bid <32 : V-block, y=bid.  Loop a=0..7, acc never reset (inclusive P3)
//   bid <64 : U-block, x=bid-32.  Loop b (inclusive over b)
//   else    : T-block, a=bid-64.  Loop b (row-prefix over b)
// fp32-exact prefixes (acc carries full precision).
template <int F>
__global__ __launch_bounds__(256) void corr_gemm(
    const unsigned short* __restrict__ Xt, const unsigned short* __restrict__ Wall,
    unsigned short* __restrict__ V, unsigned short* __restrict__ U,
    unsigned short* __restrict__ T) {
  int bid = blockIdx.x, gsh = blockIdx.y;
  int wave = threadIdx.x >> 6, lane = threadIdx.x & 63;
  int n = lane & 15, q = lane >> 4;
  int m0 = wave * 16 + q * 4;
  floatx4 acc[2];
#pragma unroll
  for (int t = 0; t < 2; ++t) acc[t] = (floatx4){0.f, 0.f, 0.f, 0.f};
  for (int i = 0; i < 8; ++i) {
    int ipos, slot;
    unsigned short* out;
    if (bid < 32) {
      int y = bid, a = i;
      int py = y > 24 ? y - 24 : 0;
      ipos = (24 + a) * 32 + y;
      slot = SLOT_AS + a * 8 + py;
      out = V + (size_t)(a * 32 + y) * 8192;
    } else if (bid < 64) {
      int x = bid - 32, b = i;
      int px = x > 24 ? x - 24 : 0;
      ipos = x * 32 + 24 + b;
      slot = SLOT_SB + px * 8 + b;
      out = U + (size_t)(b * 32 + x) * 8192;
    } else {
      int a = bid - 64, b = i;
      ipos = (24 + a) * 32 + 24 + b;
      slot = SLOT_M + a * 8 + b;
      out = T + (size_t)(a * 8 + b) * 8192;
    }
    mfma_tile<F, 2>(Xt + (size_t)ipos * 64 * F,
                    Wall + ((size_t)slot * 128 + gsh * 32) * F, acc, wave, n, q);
#pragma unroll
    for (int t = 0; t < 2; ++t) {
      int gcol = gsh * 32 + t * 16 + n;
      ushort4v w;
#pragma unroll
      for (int r = 0; r < 4; ++r) w[r] = f2bf(acc[t][r]);
      *(ushort4v*)&out[(size_t)gcol * 64 + m0] = w;  // [gcol][m] layout
    }
  }
}

// term1 + corrections + bias + leaky-relu -> bf16 [pos][m][128].
// grid (1024, 2): gs g-half split (R16 PMC: latency-bound at 15% occ).
// A fragments preloaded BEFORE the correction init (overlap cold-A).
// Corrections in [gcol][64m] layout: per-(t) ushort4 loads.
// T row-prefixed; a-prefix summed at read (<=7 slices, 49/1024 pos).
template <int F>
__global__ __launch_bounds__(256) void final_gemm(
    const unsigned short* __restrict__ Xt, const unsigned short* __restrict__ Wall,
    const unsigned short* __restrict__ V, const unsigned short* __restrict__ U,
    const unsigned short* __restrict__ T, const float* __restrict__ bias,
    unsigned short* __restrict__ Out) {
  int pos = blockIdx.x, gs = blockIdx.y;
  int x = pos >> 5, y = pos & 31;
  int wave = threadIdx.x >> 6, lane = threadIdx.x & 63;
  int n = lane & 15, q = lane >> 4;
  int m0 = wave * 16 + q * 4;
  int clsx = x < 7 ? x : (x <= 24 ? 7 : x - 17);
  int clsy = y < 7 ? y : (y <= 24 ? 7 : y - 17);
  int px = x > 24 ? x - 24 : 0;
  int py = y > 24 ? y - 24 : 0;

  // Issue A-fragment loads FIRST (HBM-cold; latency overlaps the
  // correction/bias loads below).
  const unsigned short* a_ptr =
      Xt + (size_t)pos * 64 * F + ((size_t)(wave * 16 + n)) * F + q * 8;
  short8 av[F / 32];
#pragma unroll
  for (int kk = 0; kk < F / 32; ++kk)
    av[kk] = *(const short8*)(a_ptr + kk * 32);

  // acc init = bias, then vec4 correction adds ([gcol][m] layout).
  floatx4 acc[4];
#pragma unroll
  for (int t = 0; t < 4; ++t) {
    float bv = bias[gs * 64 + t * 16 + n];
#pragma unroll
    for (int r = 0; r < 4; ++r) acc[t][r] = bv;
  }
  if (px) {
    const unsigned short* c3 = V + ((size_t)(px - 1) * 32 + y) * 8192;
#pragma unroll
    for (int t = 0; t < 4; ++t) {
      ushort4v v = *(const ushort4v*)&c3[(size_t)(gs * 64 + t * 16 + n) * 64 + m0];
#pragma unroll
      for (int r = 0; r < 4; ++r) acc[t][r] += bf2f(v[r]);
    }
  }
  if (py) {
    const unsigned short* c2 = U + ((size_t)(py - 1) * 32 + x) * 8192;
#pragma unroll
    for (int t = 0; t < 4; ++t) {
      ushort4v v = *(const ushort4v*)&c2[(size_t)(gs * 64 + t * 16 + n) * 64 + m0];
#pragma unroll
      for (int r = 0; r < 4; ++r) acc[t][r] += bf2f(v[r]);
    }
  }
  // c4: a-prefix of row-prefixed T at b=py-1, summed at read time.
  if (px && py) {
    const unsigned short* c4b = T + (size_t)(py - 1) * 8192;
    for (int a2 = 0; a2 < px; ++a2) {
#pragma unroll
      for (int t = 0; t < 4; ++t) {
        ushort4v v = *(const ushort4v*)&c4b[(size_t)a2 * 65536 +
                                            (size_t)(gs * 64 + t * 16 + n) * 64 + m0];
#pragma unroll
        for (int r = 0; r < 4; ++r) acc[t][r] += bf2f(v[r]);
      }
    }
  }

  // MFMA with preloaded A.
  const unsigned short* w_ptr =
      Wall + ((size_t)(SLOT_W1 + clsx * 15 + clsy) * 128 + gs * 64) * F +
      (size_t)n * F + q * 8;
#pragma unroll
  for (int kk = 0; kk < F / 32; ++kk) {
#pragma unroll
    for (int t = 0; t < 4; ++t) {
      short8 bv = *(const short8*)(w_ptr + (size_t)t * 16 * F + kk * 32);
      acc[t] = __builtin_amdgcn_mfma_f32_16x16x32_bf16(av[kk], bv, acc[t], 0, 0, 0);
    }
  }

  unsigned short* o = Out + (size_t)pos * 64 * 128;
#pragma unroll
  for (int t = 0; t < 4; ++t) {
    int gcol = gs * 64 + t * 16 + n;
#pragma unroll
    for (int r = 0; r < 4; ++r) {
      int m = m0 + r;  // C/D layout: row=(lane>>4)*4+reg
      float v = acc[t][r];
      v = v > 0.f ? v : 0.01f * v;
      o[(size_t)m * 128 + gcol] = f2bf(v);
    }
  }
}

extern "C" void kernel_launch(void* const* d_in, const int* in_sizes, int n_in,
                              void* d_out, int out_size, void* d_ws,
                              size_t ws_size, hipStream_t stream) {
  const void* x   = d_in[0];
  const void* mw0 = d_in[5];
  const void* mb0 = d_in[6];
  const void* jw0 = d_in[7];
  const void* jb0 = d_in[8];
  const void* mw1 = d_in[9];
  const void* mb1 = d_in[10];
  const void* jw1 = d_in[11];
  const void* jb1 = d_in[12];

  char* ws = (char*)d_ws;
  const size_t MB = 1u << 20;
  unsigned short* Xt0   = (unsigned short*)(ws + 0);        // 8.4 MB
  unsigned short* A1    = (unsigned short*)(ws + 9 * MB);   // 16.8 MB
  unsigned short* Wall0 = (unsigned short*)(ws + 26 * MB);  // 7.4 MB (448)
  unsigned short* Wall1 = (unsigned short*)(ws + 34 * MB);  // 14.7 MB (448)
  unsigned short* Out2  = (unsigned short*)(ws + 49 * MB);  // 16.8 MB
  unsigned short* PBg0  = (unsigned short*)(ws + 66 * MB);  // 2.1 MB
  unsigned short* PBg1  = (unsigned short*)(ws + 69 * MB);  // 4.2 MB
  unsigned short* L     = (unsigned short*)(ws + 74 * MB);  // 114 KB
  float* bias0 = (float*)(ws + 75 * MB);
  float* bias1 = bias0 + 128;
  int*   flag  = (int*)(bias1 + 128);
  unsigned short* V = (unsigned short*)(ws + 76 * MB);      // 4.2 MB
  unsigned short* U = (unsigned short*)(ws + 81 * MB);      // 4.2 MB
  unsigned short* T = (unsigned short*)(ws + 86 * MB);      // 1.05 MB

  dim3 tb(32, 8);
  // Fused setup + weight-pack + input-transpose (independent jobs).
  fused_prep<<<NB_SETUP + NB_PACK + NB_TIN, tb, 0, stream>>>(
      (const unsigned short*)x, (const float*)x, mw0, jw0, mw1, jw1,
      mb0, jb0, mb1, jb1, bias0, bias1, flag, L, PBg0, PBg1, Xt0);
  prep_gemm2<<<dim3(128, 7, 2), 256, 0, stream>>>(L, PBg0, PBg1, Wall0, Wall1);

  // ---- Layer 1 (F=64) ----
  corr_gemm<64><<<dim3(72, 4), 256, 0, stream>>>(Xt0, Wall0, V, U, T);
  final_gemm<64><<<dim3(1024, 2), 256, 0, stream>>>(Xt0, Wall0, V, U, T,
                                                    bias0, A1);
  // ---- Layer 2 (F=128) ----
  corr_gemm<128><<<dim3(72, 4), 256, 0, stream>>>(A1, Wall1, V, U, T);
  final_gemm<128><<<dim3(1024, 2), 256, 0, stream>>>(A1, Wall1, V, U, T,
                                                     bias1, Out2);

  // Out2 [pos=1024][m*128+g=8192] -> d_out [m][g][pos]; vec4 block (8,32).
  transpose_out<<<dim3(256, 32), dim3(8, 32), 0, stream>>>(
      Out2, (unsigned short*)d_out, (float*)d_out, 1024, 8192, flag);
}